// Round 10
// baseline (210.556 us; speedup 1.0000x reference)
//
#include <hip/hip_runtime.h>
#include <hip/hip_bf16.h>
#include <cmath>

typedef __bf16 bf16;
typedef __bf16 bf16x2 __attribute__((ext_vector_type(2)));
typedef __bf16 bf16x4 __attribute__((ext_vector_type(4)));
typedef __bf16 bf16x8 __attribute__((ext_vector_type(8)));
typedef float floatx4 __attribute__((ext_vector_type(4)));
typedef int intx4 __attribute__((ext_vector_type(4)));
typedef unsigned int uintx2 __attribute__((ext_vector_type(2)));
typedef unsigned int uintx4 __attribute__((ext_vector_type(4)));

#define MFMA_BF16(a, b, c) __builtin_amdgcn_mfma_f32_16x16x32_bf16((a), (b), (c), 0, 0, 0)

#if defined(__has_builtin)
#if __has_builtin(__builtin_amdgcn_global_load_lds)
#define HAVE_GLL 1
#endif
#if __has_builtin(__builtin_amdgcn_cvt_pk_bf16_f32)
#define HAVE_PKCVT 1
#endif
#if __has_builtin(__builtin_amdgcn_permlane32_swap) && __has_builtin(__builtin_amdgcn_permlane16_swap)
#define HAVE_PLSWAP 1
#endif
#endif

__device__ __forceinline__ void stage16(const bf16* g, bf16* ldsbase, int lane) {
#ifdef HAVE_GLL
    __builtin_amdgcn_global_load_lds((const __attribute__((address_space(1))) unsigned int*)g,
                                     (__attribute__((address_space(3))) unsigned int*)ldsbase,
                                     16, 0, 0);
#else
    *(int4*)(ldsbase + lane * 8) = *(const int4*)g;
#endif
}

// asm global loads: unsinkable (v8-proven); completion via explicit VMCNT0.
__device__ __forceinline__ float4 gload16f(const float* p) {
    float4 r;
    asm volatile("global_load_dwordx4 %0, %1, off" : "=v"(r) : "v"(p));
    return r;
}
__device__ __forceinline__ bf16x8 gload16h(const bf16* p) {
    intx4 r;
    asm volatile("global_load_dwordx4 %0, %1, off" : "=v"(r) : "v"(p));
    return __builtin_bit_cast(bf16x8, r);
}
#define VMCNT0()                                         \
    do {                                                 \
        asm volatile("s_waitcnt vmcnt(0)" ::: "memory"); \
        __builtin_amdgcn_sched_barrier(0);               \
    } while (0)

__device__ __forceinline__ unsigned pk2(float a, float b) {
    bf16x2 t;
#ifdef HAVE_PKCVT
    t = __builtin_amdgcn_cvt_pk_bf16_f32(a, b);
#else
    t[0] = (bf16)a;
    t[1] = (bf16)b;
#endif
    return __builtin_bit_cast(unsigned, t);
}

__device__ __forceinline__ bf16x8 pack8(const float4& a, const float4& b) {
    uintx4 w;
    w[0] = pk2(a.x, a.y);
    w[1] = pk2(a.z, a.w);
    w[2] = pk2(b.x, b.y);
    w[3] = pk2(b.z, b.w);
    return __builtin_bit_cast(bf16x8, w);
}

// permlane32_swap / permlane16_swap (attn transpose, verified v6-v12)
__device__ __forceinline__ uintx2 p32swap(unsigned x, unsigned y) {
#ifdef HAVE_PLSWAP
    auto r = __builtin_amdgcn_permlane32_swap(x, y, false, false);
    uintx2 o;
    o[0] = r[0];
    o[1] = r[1];
    return o;
#else
    const int lane = threadIdx.x & 63;
    const unsigned px = __shfl(x, lane ^ 32);
    const unsigned py = __shfl(y, lane ^ 32);
    uintx2 o;
    o[0] = (lane & 32) ? py : x;
    o[1] = (lane & 32) ? y : px;
    return o;
#endif
}
__device__ __forceinline__ uintx2 p16swap(unsigned x, unsigned y) {
#ifdef HAVE_PLSWAP
    auto r = __builtin_amdgcn_permlane16_swap(x, y, false, false);
    uintx2 o;
    o[0] = r[0];
    o[1] = r[1];
    return o;
#else
    const int lane = threadIdx.x & 63;
    const unsigned px = __shfl(x, lane ^ 16);
    const unsigned py = __shfl(y, lane ^ 16);
    uintx2 o;
    o[0] = (lane & 16) ? py : x;
    o[1] = (lane & 16) ? y : px;
    return o;
#endif
}

// dtype detect, wave-wide, no LDS/sync (verified rounds 0-8)
__device__ __forceinline__ int detect_bf16(const void* x) {
    const unsigned short* u = (const unsigned short*)x;
    const int lane = threadIdx.x & 63;
    const unsigned short w0 = u[4 * lane], w1 = u[4 * lane + 2];
    const int e0 = (w0 >> 7) & 0xFF, e1 = (w1 >> 7) & 0xFF;
    const unsigned long long b0 = __ballot(e0 >= 96 && e0 <= 158);
    const unsigned long long b1 = __ballot(e1 >= 96 && e1 <= 158);
    return (__popcll(b0) + __popcll(b1)) >= 90;
}

// ---------- QKV GEMM v4: PREP-FREE, B transposed via LDS scatter-writes ----------
// r9 post-mortem: tr_read B-path FAILED (absmax 1.35 -- my assumed per-lane
// tr64 semantics were wrong; flagged pre-launch as the at-risk link). v4 keeps
// prep deleted but stages B correct-BY-CONSTRUCTION: lane (k=lane>>1,
// n0=(lane&1)*8) loads W rows along contiguous n via asm dwordx4 (unsinkable),
// cvt_pk to bf16 (f=0), then 16x ds_write_b16 into lsB[n_row*32 + k] -- the
// EXACT [n][32k] layout rounds 0-8's proven ds_read_b128 reader + MFMA +
// epilogue consumed. A-path: f=1 gll (proven); f=0 reg-stage+cvt+linear write
// (re-derived: row r gets k[ah..ah+16), matches reader). Bias raw in epilogue
// (fp32 path is MORE accurate than old bf16-converted prep). Schedule: issue
// next-buf loads before compute; VMCNT0 + LDS writes after MFMAs (T14 split);
// one __syncthreads per iter.
struct QkvArgs {
    const void* xraw;
    const void* ctxraw;
    const void* W[3];     // raw Wq, Wk, Wv [k][n]
    const void* bias[3];  // raw
    bf16* out[3];
    float scale[3];
};

__global__ __launch_bounds__(256) void gemm_qkv(QkvArgs a) {
    __shared__ __align__(16) bf16 lsA[2][4096];  // [row*32 + k]
    __shared__ __align__(16) bf16 lsB[2][4096];  // [n_row*32 + k]
    const int z = blockIdx.z;
    const int f = detect_bf16(a.xraw);
    const int tid = threadIdx.x, wave = tid >> 6, lane = tid & 63;
    const int qd = lane >> 4, j = lane & 15;
    const int m0 = blockIdx.x * 128, n0 = blockIdx.y * 128;
    const int wrow = (wave & 1) * 64, wcol = (wave >> 1) * 64;

    const void* Araw = (z == 0) ? a.xraw : a.ctxraw;
    const void* Wraw = a.W[z];

    // A staging (f=1): gll, proven layout
    const int srow = wave * 16 + (lane >> 2), scol = (lane & 3) * 8;
    const bf16* agp = (const bf16*)Araw + (size_t)(m0 + srow) * 512 + scol;
    // A staging (f=0): reg-stage 16 consecutive k per lane
    const float* Af = (const float*)Araw;
    const int am = m0 + wave * 32 + (lane >> 1), ah = (lane & 1) * 16;
    // B staging (both): lane covers k-row bk, two 8-wide n chunks at bnl, bnl+16
    const int bk = lane >> 1, bnl = (lane & 1) * 8;
    const bf16* Wh = (const bf16*)Wraw;
    const float* Wf = (const float*)Wraw;
    const size_t bcol = (size_t)(n0 + wave * 32 + bnl);

    float4 ar[4], br[4];
    bf16x8 bh0, bh1;

    auto stage = [&](int buf, int k0) {
        if (f) {
            stage16(agp + k0, &lsA[buf][wave * 512], lane);
            stage16(agp + k0 + (size_t)64 * 512, &lsA[buf][wave * 512 + 2048], lane);
            const bf16* bp = Wh + (size_t)(k0 + bk) * 512 + bcol;
            bh0 = gload16h(bp);
            bh1 = gload16h(bp + 16);
        } else {
            const float* ap = Af + (size_t)am * 512 + k0 + ah;
            ar[0] = gload16f(ap);
            ar[1] = gload16f(ap + 4);
            ar[2] = gload16f(ap + 8);
            ar[3] = gload16f(ap + 12);
            const float* bp = Wf + (size_t)(k0 + bk) * 512 + bcol;
            br[0] = gload16f(bp);
            br[1] = gload16f(bp + 4);
            br[2] = gload16f(bp + 16);
            br[3] = gload16f(bp + 20);
        }
    };
    auto finish = [&](int buf) {  // call after VMCNT0()
        bf16x8 b0, b1;
        if (f) {
            b0 = bh0;
            b1 = bh1;
        } else {
            b0 = pack8(br[0], br[1]);
            b1 = pack8(br[2], br[3]);
            // A: row am, k [ah..ah+16); dest linear, conflict-light
            bf16* ad = &lsA[buf][(wave * 32 + (lane >> 1)) * 32 + ah];
            *(bf16x8*)ad = pack8(ar[0], ar[1]);
            *(bf16x8*)(ad + 8) = pack8(ar[2], ar[3]);
        }
        const int nb0 = wave * 32 + bnl;
#pragma unroll
        for (int e = 0; e < 8; ++e) {
            lsB[buf][(nb0 + e) * 32 + bk] = b0[e];
            lsB[buf][(nb0 + 16 + e) * 32 + bk] = b1[e];
        }
    };

    floatx4 acc[4][4] = {};

    stage(0, 0);
    VMCNT0();
    finish(0);
    __syncthreads();

    int cur = 0;
#pragma unroll 1
    for (int it = 0; it < 16; ++it) {
        if (it < 15) stage(cur ^ 1, (it + 1) * 32);

        bf16x8 af[4], bfr[4];
#pragma unroll
        for (int i = 0; i < 4; ++i) {
            af[i] = *(const bf16x8*)(&lsA[cur][(wrow + i * 16 + j) * 32 + qd * 8]);
            bfr[i] = *(const bf16x8*)(&lsB[cur][(wcol + i * 16 + j) * 32 + qd * 8]);
        }
        if (z < 2) {  // D[n][m]: packed-d stores
#pragma unroll
            for (int nt = 0; nt < 4; ++nt)
#pragma unroll
                for (int rf = 0; rf < 4; ++rf)
                    acc[nt][rf] = MFMA_BF16(bfr[nt], af[rf], acc[nt][rf]);
        } else {  // D[m][n]: packed-s stores
#pragma unroll
            for (int rf = 0; rf < 4; ++rf)
#pragma unroll
                for (int nt = 0; nt < 4; ++nt)
                    acc[rf][nt] = MFMA_BF16(af[rf], bfr[nt], acc[rf][nt]);
        }

        if (it < 15) {
            VMCNT0();
            finish(cur ^ 1);
        }
        __syncthreads();
        cur ^= 1;
    }

    const float scale = a.scale[z];
    bf16* __restrict__ C = a.out[z];
    if (z < 2) {
#pragma unroll
        for (int nt = 0; nt < 4; ++nt) {
            const int nb = n0 + wcol + nt * 16 + qd * 4;
            float bvf[4];
            if (f) {
                const bf16x4 t = *(const bf16x4*)((const bf16*)a.bias[z] + nb);
#pragma unroll
                for (int r = 0; r < 4; ++r) bvf[r] = (float)t[r];
            } else {
                const float4 t = *(const float4*)((const float*)a.bias[z] + nb);
                bvf[0] = t.x; bvf[1] = t.y; bvf[2] = t.z; bvf[3] = t.w;
            }
            const int h = nb >> 5, d0 = nb & 31;
#pragma unroll
            for (int rf = 0; rf < 4; ++rf) {
                const int m = m0 + wrow + rf * 16 + j;
                const int bb2 = m >> 11, t = m & 2047;
                bf16x4 pk;
#pragma unroll
                for (int r = 0; r < 4; ++r)
                    pk[r] = (bf16)((acc[nt][rf][r] + bvf[r]) * scale);
                *(bf16x4*)(&C[(((size_t)bb2 * 16 + h) * 2048 + t) * 32 + d0]) = pk;
            }
        }
    } else {
#pragma unroll
        for (int nt = 0; nt < 4; ++nt) {
            const int n = n0 + wcol + nt * 16 + j;
            const float bv = f ? (float)((const bf16*)a.bias[z])[n]
                               : ((const float*)a.bias[z])[n];
            const int h = n >> 5, d = n & 31;
#pragma unroll
            for (int rf = 0; rf < 4; ++rf) {
                const int t0 = m0 + wrow + rf * 16 + qd * 4;
                const int bb2 = t0 >> 11, s = t0 & 2047;
                bf16x4 pk;
#pragma unroll
                for (int r = 0; r < 4; ++r) pk[r] = (bf16)(acc[rf][nt][r] + bv);
                *(bf16x4*)(&C[(((size_t)bb2 * 16 + h) * 32 + d) * 2048 + s]) = pk;
            }
        }
    }
}

// ---------- attention v12 (frozen since r7): block-shared K/V, 2 chunks/phase ----------
__device__ __forceinline__ void gll16kv(const bf16* g, bf16* lds) {
#ifdef HAVE_GLL
    __builtin_amdgcn_global_load_lds((const __attribute__((address_space(1))) unsigned int*)g,
                                     (__attribute__((address_space(3))) unsigned int*)lds,
                                     16, 0, 0);
#else
    *(int4*)(lds + (threadIdx.x & 63) * 8) = *(const int4*)g;
#endif
}

__global__ __launch_bounds__(256, 4) void attn_kernel(const bf16* __restrict__ Q,
                                                      const bf16* __restrict__ Kh,
                                                      const bf16* __restrict__ Vt,
                                                      bf16* __restrict__ O) {
    const int tid = threadIdx.x;
    const int wave = tid >> 6, lane = tid & 63;
    const int qd = lane >> 4, j = lane & 15;
    const int bh = blockIdx.x;
    const int b = bh >> 4, h = bh & 15;
    const int tw = blockIdx.y * 128 + wave * 32;

    __shared__ __align__(16) bf16 lsK[2][2][2048];
    __shared__ __align__(16) bf16 lsV[2][2][2048];

    const bf16* qbase = Q + ((size_t)bh * 2048 + tw) * 32;
    const bf16* kbase = Kh + (size_t)bh * 2048 * 32;
    const bf16* vbase = Vt + (size_t)bh * 32 * 2048;

    bf16x8 qf[2];
#pragma unroll
    for (int tf = 0; tf < 2; ++tf)
        qf[tf] = *(const bf16x8*)(qbase + (size_t)(tf * 16 + j) * 32 + qd * 8);

    const bf16* ksrc = kbase + (size_t)(wave * 16 + j) * 32 + qd * 8;
    const bf16* vsrc =
        vbase + (size_t)((wave >> 1) * 16 + j) * 2048 + (wave & 1) * 32 + qd * 8;
    bf16* kdst = &lsK[0][0][wave * 512];
    bf16* vdst = &lsV[0][0][wave * 512];

    auto stage = [&](int buf, int s0) {
        gll16kv(ksrc + (size_t)s0 * 32, kdst + buf * 4096);
        gll16kv(ksrc + (size_t)(s0 + 64) * 32, kdst + buf * 4096 + 2048);
        gll16kv(vsrc + s0, vdst + buf * 4096);
        gll16kv(vsrc + s0 + 64, vdst + buf * 4096 + 2048);
    };

    bf16x8 ones;
#pragma unroll
    for (int e = 0; e < 8; ++e) ones[e] = (bf16)1.0f;

    const floatx4 zero = {0.f, 0.f, 0.f, 0.f};
    floatx4 oacc[2][2] = {};
    floatx4 dacc[2] = {};

    auto qk = [&](const bf16* lk, bf16x8* pf) {
        bf16x8 kf[4];
#pragma unroll
        for (int sf = 0; sf < 4; ++sf)
            kf[sf] = *(const bf16x8*)(lk + sf * 512 + lane * 8);
#pragma unroll
        for (int tf = 0; tf < 2; ++tf) {
            floatx4 sc[4];
#pragma unroll
            for (int sf = 0; sf < 4; ++sf) sc[sf] = MFMA_BF16(kf[sf], qf[tf], zero);
            unsigned SW[4][2];
#pragma unroll
            for (int sf = 0; sf < 4; ++sf) {
                const float e0 = __builtin_amdgcn_exp2f(sc[sf][0]);
                const float e1 = __builtin_amdgcn_exp2f(sc[sf][1]);
                const float e2 = __builtin_amdgcn_exp2f(sc[sf][2]);
                const float e3 = __builtin_amdgcn_exp2f(sc[sf][3]);
                SW[sf][0] = pk2(e0, e1);
                SW[sf][1] = pk2(e2, e3);
            }
            const uintx2 a0 = p32swap(SW[0][0], SW[1][0]);
            const uintx2 a1 = p32swap(SW[0][1], SW[1][1]);
            const uintx2 c0 = p32swap(SW[2][0], SW[3][0]);
            const uintx2 c1 = p32swap(SW[2][1], SW[3][1]);
            const uintx2 t0 = p16swap(a0[0], a0[1]);
            const uintx2 t1 = p16swap(a1[0], a1[1]);
            const uintx2 t2 = p16swap(c0[0], c0[1]);
            const uintx2 t3 = p16swap(c1[0], c1[1]);
            uintx4 w0, w1;
            w0[0] = t0[0]; w0[1] = t1[0]; w0[2] = t0[1]; w0[3] = t1[1];
            w1[0] = t2[0]; w1[1] = t3[0]; w1[2] = t2[1]; w1[3] = t3[1];
            pf[tf * 2 + 0] = __builtin_bit_cast(bf16x8, w0);
            pf[tf * 2 + 1] = __builtin_bit_cast(bf16x8, w1);
        }
    };
    auto pv = [&](const bf16* lv, const bf16x8* pf) {
        bf16x8 vf[4];
#pragma unroll
        for (int i = 0; i < 4; ++i)
            vf[i] = *(const bf16x8*)(lv + i * 512 + lane * 8);
#pragma unroll
        for (int tf = 0; tf < 2; ++tf) {
            oacc[tf][0] = MFMA_BF16(pf[tf * 2 + 0], vf[0], oacc[tf][0]);
            oacc[tf][1] = MFMA_BF16(pf[tf * 2 + 0], vf[2], oacc[tf][1]);
            dacc[tf] = MFMA_BF16(pf[tf * 2 + 0], ones, dacc[tf]);
            oacc[tf][0] = MFMA_BF16(pf[tf * 2 + 1], vf[1], oacc[tf][0]);
            oacc[tf][1] = MFMA_BF16(pf[tf * 2 + 1], vf[3], oacc[tf][1]);
            dacc[tf] = MFMA_BF16(pf[tf * 2 + 1], ones, dacc[tf]);
        }
    };

    stage(0, 0);

    int cur = 0;
#pragma unroll 1
    for (int ph = 0; ph < 16; ++ph) {
        if (ph < 15) {
            stage(cur ^ 1, (ph + 1) * 128);
            asm volatile("s_waitcnt vmcnt(4)" ::: "memory");
        } else {
            asm volatile("s_waitcnt vmcnt(0)" ::: "memory");
        }
        __builtin_amdgcn_sched_barrier(0);
        __builtin_amdgcn_s_barrier();
        __builtin_amdgcn_sched_barrier(0);

        bf16x8 pfA[4], pfB[4];
        qk(&lsK[cur][0][0], pfA);
        qk(&lsK[cur][1][0], pfB);
        pv(&lsV[cur][0][0], pfA);
        pv(&lsV[cur][1][0], pfB);

        __builtin_amdgcn_sched_barrier(0);
        __builtin_amdgcn_s_barrier();
        __builtin_amdgcn_sched_barrier(0);
        cur ^= 1;
    }

#pragma unroll
    for (int tf = 0; tf < 2; ++tf)
#pragma unroll
        for (int r = 0; r < 4; ++r) {
            const float inv = 1.0f / dacc[tf][r];
            const int t = tw + tf * 16 + qd * 4 + r;
#pragma unroll
            for (int dt = 0; dt < 2; ++dt)
                O[((size_t)b * 2048 + t) * 512 + h * 32 + dt * 16 + j] =
                    (bf16)(oacc[tf][dt][r] * inv);
        }
}

// ---------- output GEMM v4: prep-free, B transposed via LDS scatter-writes ----------
__global__ __launch_bounds__(256) void gemm_out(const bf16* __restrict__ A,
                                                const void* __restrict__ Wraw,
                                                const void* __restrict__ biasraw,
                                                void* __restrict__ C,
                                                const void* __restrict__ xraw) {
    __shared__ __align__(16) bf16 lsA[2][4096];
    __shared__ __align__(16) bf16 lsB[2][4096];  // [n_row*32 + k]
    const int f = detect_bf16(xraw);
    const int tid = threadIdx.x, wave = tid >> 6, lane = tid & 63;
    const int qd = lane >> 4, j = lane & 15;
    const int m0 = blockIdx.x * 128, n0 = blockIdx.y * 128;
    const int wrow = (wave & 1) * 64, wcol = (wave >> 1) * 64;
    const int srow = wave * 16 + (lane >> 2), scol = (lane & 3) * 8;
    const bf16* agp = A + (size_t)(m0 + srow) * 512 + scol;
    const int bk = lane >> 1, bnl = (lane & 1) * 8;
    const bf16* Wh = (const bf16*)Wraw;
    const float* Wf = (const float*)Wraw;
    const size_t bcol = (size_t)(n0 + wave * 32 + bnl);

    float4 br[4];
    bf16x8 bh0, bh1;

    auto stage = [&](int buf, int k0) {
        stage16(agp + k0, &lsA[buf][wave * 512], lane);
        stage16(agp + k0 + (size_t)64 * 512, &lsA[buf][wave * 512 + 2048], lane);
        if (f) {
            const bf16* bp = Wh + (size_t)(k0 + bk) * 512 + bcol;
            bh0 = gload16h(bp);
            bh1 = gload16h(bp + 16);
        } else {
            const float* bp = Wf + (size_t)(k0 + bk) * 512 + bcol;
            br[0] = gload16f(bp);
            br[1] = gload16f(bp + 4);
            br[2] = gload16f(bp + 16);
            br[3] = gload16f(bp + 20);
        }
    };
    auto finish = [&](int buf) {  // after VMCNT0()
        bf16x8 b0, b1;
        if (f) {
            b0 = bh0;
            b1 = bh1;
        } else {
            b0 = pack8(br[0], br[1]);
            b1 = pack8(br[2], br[3]);
        }
        const int nb0 = wave * 32 + bnl;
#pragma unroll
        for (int e = 0; e < 8; ++e) {
            lsB[buf][(nb0 + e) * 32 + bk] = b0[e];
            lsB[buf][(nb0 + 16 + e) * 32 + bk] = b1[e];
        }
    };

    floatx4 acc[4][4] = {};

    stage(0, 0);
    VMCNT0();
    finish(0);
    __syncthreads();

    int cur = 0;
#pragma unroll 1
    for (int it = 0; it < 16; ++it) {
        if (it < 15) stage(cur ^ 1, (it + 1) * 32);

        bf16x8 af[4], bfr[4];
#pragma unroll
        for (int i = 0; i < 4; ++i) {
            af[i] = *(const bf16x8*)(&lsA[cur][(wrow + i * 16 + j) * 32 + qd * 8]);
            bfr[i] = *(const bf16x8*)(&lsB[cur][(wcol + i * 16 + j) * 32 + qd * 8]);
        }
#pragma unroll
        for (int nt = 0; nt < 4; ++nt)
#pragma unroll
            for (int rf = 0; rf < 4; ++rf)
                acc[nt][rf] = MFMA_BF16(bfr[nt], af[rf], acc[nt][rf]);

        if (it < 15) {
            VMCNT0();
            finish(cur ^ 1);
        }
        __syncthreads();
        cur ^= 1;
    }

#pragma unroll
    for (int nt = 0; nt < 4; ++nt) {
        const int nb = n0 + wcol + nt * 16 + qd * 4;
        float bvf[4];
        if (f) {
            const bf16x4 t = *(const bf16x4*)((const bf16*)biasraw + nb);
#pragma unroll
            for (int r = 0; r < 4; ++r) bvf[r] = (float)t[r];
        } else {
            const float4 t = *(const float4*)((const float*)biasraw + nb);
            bvf[0] = t.x; bvf[1] = t.y; bvf[2] = t.z; bvf[3] = t.w;
        }
#pragma unroll
        for (int rf = 0; rf < 4; ++rf) {
            const int m = m0 + wrow + rf * 16 + j;
            if (f) {
                bf16x4 pk;
#pragma unroll
                for (int r = 0; r < 4; ++r) pk[r] = (bf16)(acc[nt][rf][r] + bvf[r]);
                *(bf16x4*)((bf16*)C + (size_t)m * 512 + nb) = pk;
            } else {
                float4 v;
                v.x = acc[nt][rf][0] + bvf[0];
                v.y = acc[nt][rf][1] + bvf[1];
                v.z = acc[nt][rf][2] + bvf[2];
                v.w = acc[nt][rf][3] + bvf[3];
                *(float4*)((float*)C + (size_t)m * 512 + nb) = v;
            }
        }
    }
}

extern "C" void kernel_launch(void* const* d_in, const int* in_sizes, int n_in, void* d_out,
                              int out_size, void* d_ws, size_t ws_size, hipStream_t stream) {
    char* ws = (char*)d_ws;
    bf16* aws = (bf16*)(ws + 4194304);
    bf16* qws = (bf16*)(ws + 20971520);
    bf16* kws = (bf16*)(ws + 29360128);
    bf16* vtws = (bf16*)(ws + 37748736);

    // D^-0.5 * log2(e) folded into Q so attention uses raw v_exp_f32 (2^x)
    QkvArgs qa;
    qa.xraw = d_in[0]; qa.ctxraw = d_in[1];
    qa.W[0] = d_in[2]; qa.W[1] = d_in[4]; qa.W[2] = d_in[6];
    qa.bias[0] = d_in[3]; qa.bias[1] = d_in[5]; qa.bias[2] = d_in[7];
    qa.out[0] = qws; qa.out[1] = kws; qa.out[2] = vtws;
    qa.scale[0] = 0.2550348593f; qa.scale[1] = 1.0f; qa.scale[2] = 1.0f;
    gemm_qkv<<<dim3(64, 4, 3), 256, 0, stream>>>(qa);

    attn_kernel<<<dim3(64, 16), 256, 0, stream>>>(qws, kws, vtws, aws);

    gemm_out<<<dim3(64, 4), 256, 0, stream>>>(aws, d_in[8], d_in[9], d_out, d_in[0]);
}

// Round 12
// 195.136 us; speedup vs baseline: 1.0790x; 1.0790x over previous
//
#include <hip/hip_runtime.h>
#include <hip/hip_bf16.h>
#include <cmath>

typedef __bf16 bf16;
typedef __bf16 bf16x2 __attribute__((ext_vector_type(2)));
typedef __bf16 bf16x4 __attribute__((ext_vector_type(4)));
typedef __bf16 bf16x8 __attribute__((ext_vector_type(8)));
typedef float floatx4 __attribute__((ext_vector_type(4)));
typedef int intx4 __attribute__((ext_vector_type(4)));
typedef unsigned int uintx2 __attribute__((ext_vector_type(2)));
typedef unsigned int uintx4 __attribute__((ext_vector_type(4)));

#define MFMA_BF16(a, b, c) __builtin_amdgcn_mfma_f32_16x16x32_bf16((a), (b), (c), 0, 0, 0)

#if defined(__has_builtin)
#if __has_builtin(__builtin_amdgcn_global_load_lds)
#define HAVE_GLL 1
#endif
#if __has_builtin(__builtin_amdgcn_cvt_pk_bf16_f32)
#define HAVE_PKCVT 1
#endif
#if __has_builtin(__builtin_amdgcn_permlane32_swap) && __has_builtin(__builtin_amdgcn_permlane16_swap)
#define HAVE_PLSWAP 1
#endif
#endif

__device__ __forceinline__ void stage16(const bf16* g, bf16* ldsbase, int lane) {
#ifdef HAVE_GLL
    __builtin_amdgcn_global_load_lds((const __attribute__((address_space(1))) unsigned int*)g,
                                     (__attribute__((address_space(3))) unsigned int*)ldsbase,
                                     16, 0, 0);
#else
    *(int4*)(ldsbase + lane * 8) = *(const int4*)g;
#endif
}

// asm global load: unsinkable (v8-proven); completion via explicit VMCNT0.
__device__ __forceinline__ float4 gload16f(const float* p) {
    float4 r;
    asm volatile("global_load_dwordx4 %0, %1, off" : "=v"(r) : "v"(p));
    return r;
}
#define VMCNT0()                                         \
    do {                                                 \
        asm volatile("s_waitcnt vmcnt(0)" ::: "memory"); \
        __builtin_amdgcn_sched_barrier(0);               \
    } while (0)

__device__ __forceinline__ unsigned pk2(float a, float b) {
    bf16x2 t;
#ifdef HAVE_PKCVT
    t = __builtin_amdgcn_cvt_pk_bf16_f32(a, b);
#else
    t[0] = (bf16)a;
    t[1] = (bf16)b;
#endif
    return __builtin_bit_cast(unsigned, t);
}

__device__ __forceinline__ bf16x8 pack8(const float4& a, const float4& b) {
    uintx4 w;
    w[0] = pk2(a.x, a.y);
    w[1] = pk2(a.z, a.w);
    w[2] = pk2(b.x, b.y);
    w[3] = pk2(b.z, b.w);
    return __builtin_bit_cast(bf16x8, w);
}

// permlane32_swap / permlane16_swap (attn transpose, verified v6-v12)
__device__ __forceinline__ uintx2 p32swap(unsigned x, unsigned y) {
#ifdef HAVE_PLSWAP
    auto r = __builtin_amdgcn_permlane32_swap(x, y, false, false);
    uintx2 o;
    o[0] = r[0];
    o[1] = r[1];
    return o;
#else
    const int lane = threadIdx.x & 63;
    const unsigned px = __shfl(x, lane ^ 32);
    const unsigned py = __shfl(y, lane ^ 32);
    uintx2 o;
    o[0] = (lane & 32) ? py : x;
    o[1] = (lane & 32) ? y : px;
    return o;
#endif
}
__device__ __forceinline__ uintx2 p16swap(unsigned x, unsigned y) {
#ifdef HAVE_PLSWAP
    auto r = __builtin_amdgcn_permlane16_swap(x, y, false, false);
    uintx2 o;
    o[0] = r[0];
    o[1] = r[1];
    return o;
#else
    const int lane = threadIdx.x & 63;
    const unsigned px = __shfl(x, lane ^ 16);
    const unsigned py = __shfl(y, lane ^ 16);
    uintx2 o;
    o[0] = (lane & 16) ? py : x;
    o[1] = (lane & 16) ? y : px;
    return o;
#endif
}

// dtype detect, wave-wide, no LDS/sync (verified rounds 0-10)
__device__ __forceinline__ int detect_bf16(const void* x) {
    const unsigned short* u = (const unsigned short*)x;
    const int lane = threadIdx.x & 63;
    const unsigned short w0 = u[4 * lane], w1 = u[4 * lane + 2];
    const int e0 = (w0 >> 7) & 0xFF, e1 = (w1 >> 7) & 0xFF;
    const unsigned long long b0 = __ballot(e0 >= 96 && e0 <= 158);
    const unsigned long long b1 = __ballot(e1 >= 96 && e1 <= 158);
    return (__popcll(b0) + __popcll(b1)) >= 90;
}

// ---------- prep_w: W transposes ONLY (1024 blocks; proven r0-r8 code) ----------
// r10 post-mortem: inline B-transpose cost 3.9M bank conflicts + 32 ds_write
// per lane per iter -> qkv 63us, MfmaUtil 6.9%. Weight traffic is only 4MB;
// the win of prep-deletion was killing the 48MB x/ctx round-trip, which stays
// deleted (A converts inline in qkv). So W-transpose returns as a tiny kernel.
struct PrepWArgs {
    const void* x;  // dtype probe only
    const void* W[4];
    bf16* WT[4];
};

__global__ __launch_bounds__(256) void prep_w(PrepWArgs a) {
    const int tid = threadIdx.x;
    const int f = detect_bf16(a.x);
    const int bid = blockIdx.x;
    const int w = bid >> 8, tileid = bid & 255;
    const int bx = tileid & 15, by = tileid >> 4;
    const void* __restrict__ in = a.W[w];
    bf16* __restrict__ out = a.WT[w];
    __shared__ bf16 tile[32][33];
    const int tx = tid & 31, ty = tid >> 5;
    const int x = bx * 32 + tx;
    const int y0 = by * 32;
#pragma unroll
    for (int yy = ty; yy < 32; yy += 8) {
        const size_t idx = (size_t)(y0 + yy) * 512 + x;
        const float v = f ? (float)((const bf16*)in)[idx] : ((const float*)in)[idx];
        tile[yy][tx] = (bf16)v;
    }
    __syncthreads();
    const int xo = by * 32 + tx;
    const int y1 = bx * 32;
#pragma unroll
    for (int yy = ty; yy < 32; yy += 8)
        out[(size_t)(y1 + yy) * 512 + xo] = tile[tx][yy];
}

// ---------- QKV GEMM v5: inline A-conversion + proven gll B from wT ----------
// B: gll from wT (r0-r8 layout, zero conflicts, zero finish-writes). A: f=1
// gll raw bf16 (proven); f=0 asm reg-stage fp32 + cvt_pk + b128 writes into
// STRIDE-40 padded lsA (write conflicts 8-way max vs r10's 16-way; reads
// 2-way=free). f=0 loop: issue next-buf loads at iter top, drain vmcnt AFTER
// compute, write A, one barrier -- load latency hides under 16 MFMAs. f=1
// keeps r8's counted-vmcnt(4) two-barrier loop. Raw bias in epilogue (r10).
struct QkvArgs {
    const void* xraw;
    const void* ctxraw;
    const bf16* Wt[3];    // transposed weights (prep_w)
    const void* bias[3];  // raw
    bf16* out[3];
    float scale[3];
};

__global__ __launch_bounds__(256) void gemm_qkv(QkvArgs a) {
    __shared__ __align__(16) bf16 lsA[2][128 * 40];  // stride 40 (f=0) / 32 (f=1)
    __shared__ __align__(16) bf16 lsB[2][4096];      // [n_row*32 + k]
    const int z = blockIdx.z;
    const int f = detect_bf16(a.xraw);
    const int tid = threadIdx.x, wave = tid >> 6, lane = tid & 63;
    const int qd = lane >> 4, j = lane & 15;
    const int m0 = blockIdx.x * 128, n0 = blockIdx.y * 128;
    const int wrow = (wave & 1) * 64, wcol = (wave >> 1) * 64;

    const void* Araw = (z == 0) ? a.xraw : a.ctxraw;
    const bf16* __restrict__ Wt = a.Wt[z];

    // staging sources
    const int srow = wave * 16 + (lane >> 2), scol = (lane & 3) * 8;
    const bf16* agp = (const bf16*)Araw + (size_t)(m0 + srow) * 512 + scol;  // f=1
    const bf16* bgp = Wt + (size_t)(n0 + srow) * 512 + scol;                 // both
    const float* Af = (const float*)Araw;                                    // f=0
    const int arow = wave * 32 + (lane >> 1);  // block-local A row (f=0)
    const int ah = (lane & 1) * 16;            // k sub-half

    const int SA = f ? 32 : 40;

    float4 ar[4];
    auto stageB = [&](int buf, int k0) {
        stage16(bgp + k0, &lsB[buf][wave * 512], lane);
        stage16(bgp + k0 + (size_t)64 * 512, &lsB[buf][wave * 512 + 2048], lane);
    };
    auto loadA = [&](int k0) {  // f=0: 4 asm loads (16 fp32)
        const float* ap = Af + (size_t)(m0 + arow) * 512 + k0 + ah;
        ar[0] = gload16f(ap);
        ar[1] = gload16f(ap + 4);
        ar[2] = gload16f(ap + 8);
        ar[3] = gload16f(ap + 12);
    };
    auto writeA = [&](int buf) {  // f=0, after VMCNT0
        bf16* ad = &lsA[buf][arow * 40 + ah];
        *(bf16x8*)ad = pack8(ar[0], ar[1]);
        *(bf16x8*)(ad + 8) = pack8(ar[2], ar[3]);
    };
    auto stageA1 = [&](int buf, int k0) {  // f=1: gll
        stage16(agp + k0, &lsA[buf][wave * 512], lane);
        stage16(agp + k0 + (size_t)64 * 512, &lsA[buf][wave * 512 + 2048], lane);
    };

    floatx4 acc[4][4] = {};

    auto compute = [&](int cur) {
        bf16x8 af[4], bfr[4];
#pragma unroll
        for (int i = 0; i < 4; ++i) {
            af[i] = *(const bf16x8*)(&lsA[cur][(wrow + i * 16 + j) * SA + qd * 8]);
            bfr[i] = *(const bf16x8*)(&lsB[cur][(wcol + i * 16 + j) * 32 + qd * 8]);
        }
        if (z < 2) {  // D[n][m]: packed-d stores
#pragma unroll
            for (int nt = 0; nt < 4; ++nt)
#pragma unroll
                for (int rf = 0; rf < 4; ++rf)
                    acc[nt][rf] = MFMA_BF16(bfr[nt], af[rf], acc[nt][rf]);
        } else {  // D[m][n]: packed-s stores
#pragma unroll
            for (int rf = 0; rf < 4; ++rf)
#pragma unroll
                for (int nt = 0; nt < 4; ++nt)
                    acc[rf][nt] = MFMA_BF16(af[rf], bfr[nt], acc[rf][nt]);
        }
    };

    if (f) {
        // r8-proven counted-vmcnt loop (4 gll/iter)
        stageA1(0, 0);
        stageB(0, 0);
        int cur = 0;
#pragma unroll 1
        for (int it = 0; it < 16; ++it) {
            if (it < 15) {
                stageA1(cur ^ 1, (it + 1) * 32);
                stageB(cur ^ 1, (it + 1) * 32);
                asm volatile("s_waitcnt vmcnt(4)" ::: "memory");
            } else {
                asm volatile("s_waitcnt vmcnt(0)" ::: "memory");
            }
            __builtin_amdgcn_sched_barrier(0);
            __builtin_amdgcn_s_barrier();
            __builtin_amdgcn_sched_barrier(0);
            compute(cur);
            __builtin_amdgcn_sched_barrier(0);
            __builtin_amdgcn_s_barrier();
            __builtin_amdgcn_sched_barrier(0);
            cur ^= 1;
        }
    } else {
        // drain-after-compute loop: loads span the MFMAs; 1 barrier/iter
        stageB(0, 0);
        loadA(0);
        VMCNT0();
        writeA(0);
        __syncthreads();
        int cur = 0;
#pragma unroll 1
        for (int it = 0; it < 16; ++it) {
            if (it < 15) {
                stageB(cur ^ 1, (it + 1) * 32);
                loadA((it + 1) * 32);
            }
            compute(cur);
            if (it < 15) {
                VMCNT0();
                writeA(cur ^ 1);
            }
            __syncthreads();
            cur ^= 1;
        }
    }

    const float scale = a.scale[z];
    bf16* __restrict__ C = a.out[z];
    if (z < 2) {
#pragma unroll
        for (int nt = 0; nt < 4; ++nt) {
            const int nb = n0 + wcol + nt * 16 + qd * 4;
            float bvf[4];
            if (f) {
                const bf16x4 t = *(const bf16x4*)((const bf16*)a.bias[z] + nb);
#pragma unroll
                for (int r = 0; r < 4; ++r) bvf[r] = (float)t[r];
            } else {
                const float4 t = *(const float4*)((const float*)a.bias[z] + nb);
                bvf[0] = t.x; bvf[1] = t.y; bvf[2] = t.z; bvf[3] = t.w;
            }
            const int h = nb >> 5, d0 = nb & 31;
#pragma unroll
            for (int rf = 0; rf < 4; ++rf) {
                const int m = m0 + wrow + rf * 16 + j;
                const int bb2 = m >> 11, t = m & 2047;
                bf16x4 pk;
#pragma unroll
                for (int r = 0; r < 4; ++r)
                    pk[r] = (bf16)((acc[nt][rf][r] + bvf[r]) * scale);
                *(bf16x4*)(&C[(((size_t)bb2 * 16 + h) * 2048 + t) * 32 + d0]) = pk;
            }
        }
    } else {
#pragma unroll
        for (int nt = 0; nt < 4; ++nt) {
            const int n = n0 + wcol + nt * 16 + j;
            const float bv = f ? (float)((const bf16*)a.bias[z])[n]
                               : ((const float*)a.bias[z])[n];
            const int h = n >> 5, d = n & 31;
#pragma unroll
            for (int rf = 0; rf < 4; ++rf) {
                const int t0 = m0 + wrow + rf * 16 + qd * 4;
                const int bb2 = t0 >> 11, s = t0 & 2047;
                bf16x4 pk;
#pragma unroll
                for (int r = 0; r < 4; ++r) pk[r] = (bf16)(acc[rf][nt][r] + bv);
                *(bf16x4*)(&C[(((size_t)bb2 * 16 + h) * 32 + d) * 2048 + s]) = pk;
            }
        }
    }
}

// ---------- attention v12 (frozen since r7): block-shared K/V, 2 chunks/phase ----------
__device__ __forceinline__ void gll16kv(const bf16* g, bf16* lds) {
#ifdef HAVE_GLL
    __builtin_amdgcn_global_load_lds((const __attribute__((address_space(1))) unsigned int*)g,
                                     (__attribute__((address_space(3))) unsigned int*)lds,
                                     16, 0, 0);
#else
    *(int4*)(lds + (threadIdx.x & 63) * 8) = *(const int4*)g;
#endif
}

__global__ __launch_bounds__(256, 4) void attn_kernel(const bf16* __restrict__ Q,
                                                      const bf16* __restrict__ Kh,
                                                      const bf16* __restrict__ Vt,
                                                      bf16* __restrict__ O) {
    const int tid = threadIdx.x;
    const int wave = tid >> 6, lane = tid & 63;
    const int qd = lane >> 4, j = lane & 15;
    const int bh = blockIdx.x;
    const int b = bh >> 4, h = bh & 15;
    const int tw = blockIdx.y * 128 + wave * 32;

    __shared__ __align__(16) bf16 lsK[2][2][2048];
    __shared__ __align__(16) bf16 lsV[2][2][2048];

    const bf16* qbase = Q + ((size_t)bh * 2048 + tw) * 32;
    const bf16* kbase = Kh + (size_t)bh * 2048 * 32;
    const bf16* vbase = Vt + (size_t)bh * 32 * 2048;

    bf16x8 qf[2];
#pragma unroll
    for (int tf = 0; tf < 2; ++tf)
        qf[tf] = *(const bf16x8*)(qbase + (size_t)(tf * 16 + j) * 32 + qd * 8);

    const bf16* ksrc = kbase + (size_t)(wave * 16 + j) * 32 + qd * 8;
    const bf16* vsrc =
        vbase + (size_t)((wave >> 1) * 16 + j) * 2048 + (wave & 1) * 32 + qd * 8;
    bf16* kdst = &lsK[0][0][wave * 512];
    bf16* vdst = &lsV[0][0][wave * 512];

    auto stage = [&](int buf, int s0) {
        gll16kv(ksrc + (size_t)s0 * 32, kdst + buf * 4096);
        gll16kv(ksrc + (size_t)(s0 + 64) * 32, kdst + buf * 4096 + 2048);
        gll16kv(vsrc + s0, vdst + buf * 4096);
        gll16kv(vsrc + s0 + 64, vdst + buf * 4096 + 2048);
    };

    bf16x8 ones;
#pragma unroll
    for (int e = 0; e < 8; ++e) ones[e] = (bf16)1.0f;

    const floatx4 zero = {0.f, 0.f, 0.f, 0.f};
    floatx4 oacc[2][2] = {};
    floatx4 dacc[2] = {};

    auto qk = [&](const bf16* lk, bf16x8* pf) {
        bf16x8 kf[4];
#pragma unroll
        for (int sf = 0; sf < 4; ++sf)
            kf[sf] = *(const bf16x8*)(lk + sf * 512 + lane * 8);
#pragma unroll
        for (int tf = 0; tf < 2; ++tf) {
            floatx4 sc[4];
#pragma unroll
            for (int sf = 0; sf < 4; ++sf) sc[sf] = MFMA_BF16(kf[sf], qf[tf], zero);
            unsigned SW[4][2];
#pragma unroll
            for (int sf = 0; sf < 4; ++sf) {
                const float e0 = __builtin_amdgcn_exp2f(sc[sf][0]);
                const float e1 = __builtin_amdgcn_exp2f(sc[sf][1]);
                const float e2 = __builtin_amdgcn_exp2f(sc[sf][2]);
                const float e3 = __builtin_amdgcn_exp2f(sc[sf][3]);
                SW[sf][0] = pk2(e0, e1);
                SW[sf][1] = pk2(e2, e3);
            }
            const uintx2 a0 = p32swap(SW[0][0], SW[1][0]);
            const uintx2 a1 = p32swap(SW[0][1], SW[1][1]);
            const uintx2 c0 = p32swap(SW[2][0], SW[3][0]);
            const uintx2 c1 = p32swap(SW[2][1], SW[3][1]);
            const uintx2 t0 = p16swap(a0[0], a0[1]);
            const uintx2 t1 = p16swap(a1[0], a1[1]);
            const uintx2 t2 = p16swap(c0[0], c0[1]);
            const uintx2 t3 = p16swap(c1[0], c1[1]);
            uintx4 w0, w1;
            w0[0] = t0[0]; w0[1] = t1[0]; w0[2] = t0[1]; w0[3] = t1[1];
            w1[0] = t2[0]; w1[1] = t3[0]; w1[2] = t2[1]; w1[3] = t3[1];
            pf[tf * 2 + 0] = __builtin_bit_cast(bf16x8, w0);
            pf[tf * 2 + 1] = __builtin_bit_cast(bf16x8, w1);
        }
    };
    auto pv = [&](const bf16* lv, const bf16x8* pf) {
        bf16x8 vf[4];
#pragma unroll
        for (int i = 0; i < 4; ++i)
            vf[i] = *(const bf16x8*)(lv + i * 512 + lane * 8);
#pragma unroll
        for (int tf = 0; tf < 2; ++tf) {
            oacc[tf][0] = MFMA_BF16(pf[tf * 2 + 0], vf[0], oacc[tf][0]);
            oacc[tf][1] = MFMA_BF16(pf[tf * 2 + 0], vf[2], oacc[tf][1]);
            dacc[tf] = MFMA_BF16(pf[tf * 2 + 0], ones, dacc[tf]);
            oacc[tf][0] = MFMA_BF16(pf[tf * 2 + 1], vf[1], oacc[tf][0]);
            oacc[tf][1] = MFMA_BF16(pf[tf * 2 + 1], vf[3], oacc[tf][1]);
            dacc[tf] = MFMA_BF16(pf[tf * 2 + 1], ones, dacc[tf]);
        }
    };

    stage(0, 0);

    int cur = 0;
#pragma unroll 1
    for (int ph = 0; ph < 16; ++ph) {
        if (ph < 15) {
            stage(cur ^ 1, (ph + 1) * 128);
            asm volatile("s_waitcnt vmcnt(4)" ::: "memory");
        } else {
            asm volatile("s_waitcnt vmcnt(0)" ::: "memory");
        }
        __builtin_amdgcn_sched_barrier(0);
        __builtin_amdgcn_s_barrier();
        __builtin_amdgcn_sched_barrier(0);

        bf16x8 pfA[4], pfB[4];
        qk(&lsK[cur][0][0], pfA);
        qk(&lsK[cur][1][0], pfB);
        pv(&lsV[cur][0][0], pfA);
        pv(&lsV[cur][1][0], pfB);

        __builtin_amdgcn_sched_barrier(0);
        __builtin_amdgcn_s_barrier();
        __builtin_amdgcn_sched_barrier(0);
        cur ^= 1;
    }

#pragma unroll
    for (int tf = 0; tf < 2; ++tf)
#pragma unroll
        for (int r = 0; r < 4; ++r) {
            const float inv = 1.0f / dacc[tf][r];
            const int t = tw + tf * 16 + qd * 4 + r;
#pragma unroll
            for (int dt = 0; dt < 2; ++dt)
                O[((size_t)b * 2048 + t) * 512 + h * 32 + dt * 16 + j] =
                    (bf16)(oacc[tf][dt][r] * inv);
        }
}

// ---------- output GEMM v5: gll A + gll B from woT, raw bias ----------
__global__ __launch_bounds__(256) void gemm_out(const bf16* __restrict__ A,
                                                const bf16* __restrict__ Wt,
                                                const void* __restrict__ biasraw,
                                                void* __restrict__ C,
                                                const void* __restrict__ xraw) {
    __shared__ __align__(16) bf16 lA[2][128 * 32];
    __shared__ __align__(16) bf16 lB[2][128 * 32];
    const int oflag = detect_bf16(xraw);
    const int tid = threadIdx.x, wave = tid >> 6, lane = tid & 63;
    const int qd = lane >> 4, j = lane & 15;
    const int m0 = blockIdx.x * 128, n0 = blockIdx.y * 128;
    const int wrow = (wave & 1) * 64, wcol = (wave >> 1) * 64;
    const int srow = wave * 16 + (lane >> 2);
    const int scol = (lane & 3) * 8;
    const bf16* agp = A + (size_t)(m0 + srow) * 512 + scol;
    const bf16* bgp = Wt + (size_t)(n0 + srow) * 512 + scol;

    auto stage = [&](int buf, int k0) {
        stage16(agp + k0, &lA[buf][wave * 512], lane);
        stage16(agp + k0 + (size_t)64 * 512, &lA[buf][wave * 512 + 2048], lane);
        stage16(bgp + k0, &lB[buf][wave * 512], lane);
        stage16(bgp + k0 + (size_t)64 * 512, &lB[buf][wave * 512 + 2048], lane);
    };

    floatx4 acc[4][4] = {};

    stage(0, 0);
    int cur = 0;
#pragma unroll 1
    for (int it = 0; it < 16; ++it) {
        if (it < 15) {
            stage(cur ^ 1, (it + 1) * 32);
            asm volatile("s_waitcnt vmcnt(4)" ::: "memory");
        } else {
            asm volatile("s_waitcnt vmcnt(0)" ::: "memory");
        }
        __builtin_amdgcn_sched_barrier(0);
        __builtin_amdgcn_s_barrier();
        __builtin_amdgcn_sched_barrier(0);

        bf16x8 af[4], bfr[4];
#pragma unroll
        for (int i = 0; i < 4; ++i) {
            af[i] = *(const bf16x8*)(&lA[cur][(wrow + i * 16 + j) * 32 + qd * 8]);
            bfr[i] = *(const bf16x8*)(&lB[cur][(wcol + i * 16 + j) * 32 + qd * 8]);
        }
#pragma unroll
        for (int nt = 0; nt < 4; ++nt)
#pragma unroll
            for (int rf = 0; rf < 4; ++rf)
                acc[nt][rf] = MFMA_BF16(bfr[nt], af[rf], acc[nt][rf]);

        __builtin_amdgcn_sched_barrier(0);
        __builtin_amdgcn_s_barrier();
        __builtin_amdgcn_sched_barrier(0);
        cur ^= 1;
    }

#pragma unroll
    for (int nt = 0; nt < 4; ++nt) {
        const int nb = n0 + wcol + nt * 16 + qd * 4;
        float bvf[4];
        if (oflag) {
            const bf16x4 t = *(const bf16x4*)((const bf16*)biasraw + nb);
#pragma unroll
            for (int r = 0; r < 4; ++r) bvf[r] = (float)t[r];
        } else {
            const float4 t = *(const float4*)((const float*)biasraw + nb);
            bvf[0] = t.x; bvf[1] = t.y; bvf[2] = t.z; bvf[3] = t.w;
        }
#pragma unroll
        for (int rf = 0; rf < 4; ++rf) {
            const int m = m0 + wrow + rf * 16 + j;
            if (oflag) {
                bf16x4 pk;
#pragma unroll
                for (int r = 0; r < 4; ++r) pk[r] = (bf16)(acc[nt][rf][r] + bvf[r]);
                *(bf16x4*)((bf16*)C + (size_t)m * 512 + nb) = pk;
            } else {
                float4 v;
                v.x = acc[nt][rf][0] + bvf[0];
                v.y = acc[nt][rf][1] + bvf[1];
                v.z = acc[nt][rf][2] + bvf[2];
                v.w = acc[nt][rf][3] + bvf[3];
                *(float4*)((float*)C + (size_t)m * 512 + nb) = v;
            }
        }
    }
}

extern "C" void kernel_launch(void* const* d_in, const int* in_sizes, int n_in, void* d_out,
                              int out_size, void* d_ws, size_t ws_size, hipStream_t stream) {
    char* ws = (char*)d_ws;
    bf16* wqT = (bf16*)(ws + 1048576);
    bf16* wkT = (bf16*)(ws + 1572864);
    bf16* wvT = (bf16*)(ws + 2097152);
    bf16* woT = (bf16*)(ws + 2621440);
    bf16* aws = (bf16*)(ws + 4194304);
    bf16* qws = (bf16*)(ws + 20971520);
    bf16* kws = (bf16*)(ws + 29360128);
    bf16* vtws = (bf16*)(ws + 37748736);

    PrepWArgs pw;
    pw.x = d_in[0];
    pw.W[0] = d_in[2]; pw.W[1] = d_in[4]; pw.W[2] = d_in[6]; pw.W[3] = d_in[8];
    pw.WT[0] = wqT; pw.WT[1] = wkT; pw.WT[2] = wvT; pw.WT[3] = woT;
    prep_w<<<1024, 256, 0, stream>>>(pw);

    // D^-0.5 * log2(e) folded into Q so attention uses raw v_exp_f32 (2^x)
    QkvArgs qa;
    qa.xraw = d_in[0]; qa.ctxraw = d_in[1];
    qa.Wt[0] = wqT; qa.Wt[1] = wkT; qa.Wt[2] = wvT;
    qa.bias[0] = d_in[3]; qa.bias[1] = d_in[5]; qa.bias[2] = d_in[7];
    qa.out[0] = qws; qa.out[1] = kws; qa.out[2] = vtws;
    qa.scale[0] = 0.2550348593f; qa.scale[1] = 1.0f; qa.scale[2] = 1.0f;
    gemm_qkv<<<dim3(64, 4, 3), 256, 0, stream>>>(qa);

    attn_kernel<<<dim3(64, 16), 256, 0, stream>>>(qws, kws, vtws, aws);

    gemm_out<<<dim3(64, 4), 256, 0, stream>>>(aws, woT, d_in[9], d_out, d_in[0]);
}